// Round 1
// 957.722 us; speedup vs baseline: 1.0528x; 1.0528x over previous
//
#include <hip/hip_runtime.h>

typedef __bf16 bf16_t;
typedef __bf16 bf16x4 __attribute__((ext_vector_type(4)));
typedef __bf16 bf16x8 __attribute__((ext_vector_type(8)));
typedef float floatx4 __attribute__((ext_vector_type(4)));

__device__ __forceinline__ float bf2f(bf16_t x) { return (float)x; }
__device__ __forceinline__ bf16_t f2bf(float x) { return (bf16_t)x; }

// async 16B global -> LDS (global_load_lds_dwordx4). LDS dst must be
// wave-uniform base + lane*16 (m97 pattern); global src may be per-lane.
__device__ __forceinline__ void async_copy16(const bf16_t* g, bf16_t* l) {
    __builtin_amdgcn_global_load_lds(
        (const __attribute__((address_space(1))) unsigned int*)g,
        (__attribute__((address_space(3))) unsigned int*)l, 16, 0, 0);
}

// ---------------------------------------------------------------------------
// fp32 -> bf16 elementwise convert (8 elems/thread, 16B stores). n8 = n/8.
// ---------------------------------------------------------------------------
__global__ __launch_bounds__(256) void cvt_f32_bf16(const float* __restrict__ in,
                                                    bf16_t* __restrict__ out,
                                                    int n8) {
    int i = blockIdx.x * blockDim.x + threadIdx.x;
    if (i >= n8) return;
    const float4* p = (const float4*)in + (size_t)i * 2;
    float4 a = p[0], b = p[1];
    bf16x8 v;
    v[0] = f2bf(a.x); v[1] = f2bf(a.y); v[2] = f2bf(a.z); v[3] = f2bf(a.w);
    v[4] = f2bf(b.x); v[5] = f2bf(b.y); v[6] = f2bf(b.z); v[7] = f2bf(b.w);
    *(bf16x8*)(out + (size_t)i * 8) = v;
}

// ---------------------------------------------------------------------------
// B^T GEMM, m97 structure: 128x128 tile, BK=32, 4 waves, 4x4 acc,
// global_load_lds width-16 staging.  (unchanged this round)
// ---------------------------------------------------------------------------
template <typename OT>
__global__ __launch_bounds__(256) void gemm_bt(const bf16_t* __restrict__ A,
                                               const bf16_t* __restrict__ B,
                                               OT* __restrict__ C,
                                               int M, int N, int K) {
    __shared__ __attribute__((aligned(16))) bf16_t As[128 * 32];
    __shared__ __attribute__((aligned(16))) bf16_t Bs[128 * 32];
    const int tid = threadIdx.x;
    const int lane = tid & 63;
    const int w = tid >> 6;
    const int l15 = lane & 15, qd = lane >> 4;
    const int tm = blockIdx.y * 128, tn = blockIdx.x * 128;
    const int wm = (w >> 1) * 64, wn = (w & 1) * 64;

    floatx4 acc[4][4] = {};

    for (int k0 = 0; k0 < K; k0 += 32) {
#pragma unroll
        for (int it = 0; it < 2; ++it) {
            int c = it * 256 + tid;          // 512 chunks of 16B per matrix
            int row = c >> 2, col = (c & 3) * 8;
            async_copy16(&A[(size_t)(tm + row) * K + k0 + col], &As[c * 8]);
            async_copy16(&B[(size_t)(tn + row) * K + k0 + col], &Bs[c * 8]);
        }
        __syncthreads();   // compiler emits vmcnt(0) drain before s_barrier
        bf16x8 af[4], bfr[4];
#pragma unroll
        for (int i = 0; i < 4; i++)
            af[i] = *(const bf16x8*)&As[(wm + i * 16 + l15) * 32 + qd * 8];
#pragma unroll
        for (int j = 0; j < 4; j++)
            bfr[j] = *(const bf16x8*)&Bs[(wn + j * 16 + l15) * 32 + qd * 8];
#pragma unroll
        for (int i = 0; i < 4; i++)
#pragma unroll
            for (int j = 0; j < 4; j++)
                acc[i][j] = __builtin_amdgcn_mfma_f32_16x16x32_bf16(
                    af[i], bfr[j], acc[i][j], 0, 0, 0);
        __syncthreads();
    }
    // C/D layout: col = lane&15, row = quad*4 + reg  (m89/m91 verified)
#pragma unroll
    for (int i = 0; i < 4; i++) {
        int row = tm + wm + i * 16 + qd * 4;
#pragma unroll
        for (int j = 0; j < 4; j++) {
            int col = tn + wn + j * 16 + l15;
#pragma unroll
            for (int r = 0; r < 4; r++)
                C[(size_t)(row + r) * N + col] = (OT)acc[i][j][r];
        }
    }
}

// ---------------------------------------------------------------------------
// Reference-faithful "norm" + RoPE + layout transform.
// NEW: the attention scale (1/sqrt(128)) AND log2(e) are folded into Q here
// (rope is linear, so scaling before the rotation is exact).  flash_attn then
// runs its softmax in base-2 with NO per-score scaling:
//   softmax_2(s * log2e) == softmax_e(s).
// ---------------------------------------------------------------------------
__global__ __launch_bounds__(256) void rmsrope(const bf16_t* __restrict__ qkv,
                                               const float* __restrict__ qw,
                                               const float* __restrict__ kw,
                                               bf16_t* __restrict__ q_r,
                                               bf16_t* __restrict__ k_r,
                                               bf16_t* __restrict__ v_r) {
    const int tid = threadIdx.x, lane = tid & 63, w = tid >> 6;
    const int slot = blockIdx.x * 4 + w;       // [0, 163840)
    const int row = slot / 40;
    const int hs = slot - row * 40;
    const int b = row >> 11, t = row & 2047;
    const bf16_t* src = qkv + (size_t)row * 5120 + hs * 128;

    if (hs >= 36) {  // v: passthrough reshape
        size_t dst = ((size_t)((b * 4 + (hs - 36)) * 2048 + t)) * 128;
        v_r[dst + lane] = src[lane];
        v_r[dst + lane + 64] = src[lane + 64];
        return;
    }
    float x1 = bf2f(src[lane]);
    float x2 = bf2f(src[lane + 64]);
    float ss = x1 * x1 + x2 * x2;
#pragma unroll
    for (int off = 1; off < 64; off <<= 1) ss += __shfl_xor(ss, off);
    const float rr = rsqrtf(ss * (1.0f / 128.0f) + 1e-6f);

    const float* wp;
    bf16_t* dstp;
    float sc;
    if (hs < 32) {
        wp = qw + hs * 128;
        dstp = q_r + ((size_t)((b * 32 + hs) * 2048 + t)) * 128;
        sc = rr * (0.08838834764831845f * 1.4426950408889634f);  // SCALE*log2e
    } else {
        wp = kw + (hs - 32) * 128;
        dstp = k_r + ((size_t)((b * 4 + (hs - 32)) * 2048 + t)) * 128;
        sc = rr;
    }
    float n1 = sc * wp[lane];
    float n2 = sc * wp[lane + 64];
    float inv_freq = exp2f((float)lane * -0.20762050593046f);
    float th = (float)t * inv_freq;
    float sn, cs;
    sincosf(th, &sn, &cs);
    dstp[lane] = f2bf(n1 * cs - n2 * sn);
    dstp[lane + 64] = f2bf(n1 * sn + n2 * cs);
}

// ---------------------------------------------------------------------------
// Flash attention v3.  Changes this round (DS-pipe traffic was the limiter):
//  * K tile staged via global_load_lds (async DMA, no VGPR round-trip, no
//    ds_writes) into an UNPADDED [64][128] Ks with XOR-swizzle: linear LDS
//    dest + inverse-swizzled global source + swizzled ds_read (rule #21).
//    Read conflicts: rows l15 / l15+8 share a 16B slot -> 2-way (free, m136).
//  * Row-sums via ones-column MFMA (l = P @ 1) accumulated alongside O with
//    the same alpha rescale -> removes the 4-step sum shuffle-reduce
//    (-32 ds_swizzle / wave-iter) and its dependency chain.
//  * Defer-max (T13): wave-uniform skip of max-update + O/l rescale when the
//    tile max grows by < 8 (nats) = 11.5 (log2 units).  P bounded by 2^11.5,
//    bf16 is scale-invariant so relative precision is unchanged.
//  * Scores arrive pre-scaled by SCALE*log2e -> softmax uses exp2f directly
//    (v_exp_f32, no ln2 multiplies).
// LDS: 16384 + 18432 + 18432 = 53248 B -> 3 blocks/CU fit (3x53248 < 160K).
// ---------------------------------------------------------------------------
__global__ __launch_bounds__(256, 2) void flash_attn(const bf16_t* __restrict__ Qr,
                                                     const bf16_t* __restrict__ Kr,
                                                     const bf16_t* __restrict__ Vr,
                                                     bf16_t* __restrict__ Oo) {
    __shared__ __attribute__((aligned(16))) bf16_t Ks[64 * 128];   // XOR-swizzled
    __shared__ __attribute__((aligned(16))) bf16_t Vts[128 * 72];  // Vts[d][pi(k)]
    __shared__ __attribute__((aligned(16))) bf16_t Ps[4][32 * 72]; // Ps[q][pi(k)]
    const int tid = threadIdx.x, lane = tid & 63, w = tid >> 6;
    const int l15 = lane & 15, qd = lane >> 4;
    const int qt = blockIdx.x, bh = blockIdx.y;
    const int b = bh >> 5, h = bh & 31;
    const int kvh = h >> 3;  // GROUP = 8
    const bf16_t* Qb = Qr + ((size_t)(b * 32 + h) * 2048 + qt * 128) * 128;
    const bf16_t* Kb = Kr + ((size_t)(b * 4 + kvh) * 2048) * 128;
    const bf16_t* Vb = Vr + ((size_t)(b * 4 + kvh) * 2048) * 128;
    const int wrow = w * 32;
    const int pi = l15 * 4 + qd;            // pi(lane) for V transpose writes

    // Q fragments in registers: A[m=l15][k=qd*8+j], 32 rows x 128 k per wave.
    bf16x8 qf[2][4];
#pragma unroll
    for (int i = 0; i < 2; i++)
#pragma unroll
        for (int kk = 0; kk < 4; kk++)
            qf[i][kk] = *(const bf16x8*)&Qb[(size_t)(wrow + i * 16 + l15) * 128 +
                                            kk * 32 + qd * 8];

    bf16x8 onef;
#pragma unroll
    for (int e = 0; e < 8; ++e) onef[e] = f2bf(1.0f);

    float m_s[2][4];
    floatx4 lacc[2] = {};        // row-sums, accumulated by ones-column MFMA
    floatx4 oacc[2][8] = {};
#pragma unroll
    for (int i = 0; i < 2; i++)
#pragma unroll
        for (int r = 0; r < 4; r++) m_s[i][r] = -1e30f;

    for (int kt = 0; kt < 32; ++kt) {
        __syncthreads();  // prev iteration's reads of Ks/Vts done
        // K tile (64x128) -> Ks via async DMA.  Linear LDS dest (thread c
        // writes bytes [c*16, c*16+16)); global source pre-swizzled with the
        // SAME involution the reads apply: col_byte ^= (row&7)<<4.
#pragma unroll
        for (int it = 0; it < 4; ++it) {
            int cc = it * 256 + tid;                 // 1024 chunks of 16B
            int row = cc >> 4;
            int xb = ((cc & 15) * 16) ^ ((row & 7) << 4);
            async_copy16(&Kb[(size_t)(kt * 64 + row) * 128 + (xb >> 1)],
                         &Ks[cc * 8]);
        }
        // stage V transposed with pi: Vts[d][pi(k)] = V[k][d]  (VGPR path)
#pragma unroll
        for (int it = 0; it < 4; ++it) {
            int d0 = (it * 4 + w) * 8;
            bf16x8 v = *(const bf16x8*)&Vb[(size_t)(kt * 64 + lane) * 128 + d0];
#pragma unroll
            for (int e = 0; e < 8; ++e) Vts[(d0 + e) * 72 + pi] = v[e];
        }
        __syncthreads();  // vmcnt(0) drain covers the K DMA + V stores

        // S = Q K^T for this wave's 32 rows x 64 keys (scores pre-scaled)
        floatx4 sacc[2][4] = {};
#pragma unroll
        for (int kk = 0; kk < 4; kk++) {
            bf16x8 bfr[4];
#pragma unroll
            for (int j = 0; j < 4; j++) {
                int rr2 = j * 16 + l15;
                int xb = (kk * 64 + qd * 16) ^ ((rr2 & 7) << 4);
                bfr[j] = *(const bf16x8*)&Ks[rr2 * 128 + (xb >> 1)];
            }
#pragma unroll
            for (int i = 0; i < 2; i++)
#pragma unroll
                for (int j = 0; j < 4; j++)
                    sacc[i][j] = __builtin_amdgcn_mfma_f32_16x16x32_bf16(
                        qf[i][kk], bfr[j], sacc[i][j], 0, 0, 0);
        }

        // Pass 1: per-row tile max (4-step shuffle over the 16-lane group).
        float mxv[2][4];
        int fneed = 0;
#pragma unroll
        for (int i = 0; i < 2; i++)
#pragma unroll
            for (int r = 0; r < 4; r++) {
                float mx = fmaxf(fmaxf(sacc[i][0][r], sacc[i][1][r]),
                                 fmaxf(sacc[i][2][r], sacc[i][3][r]));
#pragma unroll
                for (int off = 1; off < 16; off <<= 1)
                    mx = fmaxf(mx, __shfl_xor(mx, off));
                mxv[i][r] = mx;
                fneed |= (mx > m_s[i][r] + 11.5f);   // 8 nats in log2 units
            }
        // Defer-max: wave-uniform rescale only when some row's max grew.
        if (__any(fneed)) {
#pragma unroll
            for (int i = 0; i < 2; i++)
#pragma unroll
                for (int r = 0; r < 4; r++) {
                    float mnew = fmaxf(m_s[i][r], mxv[i][r]);
                    float alpha = exp2f(m_s[i][r] - mnew);
                    m_s[i][r] = mnew;
#pragma unroll
                    for (int jo = 0; jo < 8; jo++) oacc[i][jo][r] *= alpha;
                    lacc[i][r] *= alpha;
                }
        }
        // Pass 2: P = 2^(s - m), bf16, one 8B store per row (pi-order).
#pragma unroll
        for (int i = 0; i < 2; i++)
#pragma unroll
            for (int r = 0; r < 4; r++) {
                float m = m_s[i][r];
                bf16x4 pv;
                pv[0] = f2bf(exp2f(sacc[i][0][r] - m));
                pv[1] = f2bf(exp2f(sacc[i][1][r] - m));
                pv[2] = f2bf(exp2f(sacc[i][2][r] - m));
                pv[3] = f2bf(exp2f(sacc[i][3][r] - m));
                *(bf16x4*)&Ps[w][(i * 16 + qd * 4 + r) * 72 + l15 * 4] = pv;
            }
        // No barrier: Ps[w] is wave-private; same-wave DS ops are ordered.

        // O += P V ; l += P 1  (ones-column replaces the sum shuffle-reduce)
#pragma unroll
        for (int kk = 0; kk < 64; kk += 32) {
            bf16x8 pf[2], vf[8];
#pragma unroll
            for (int i = 0; i < 2; i++)
                pf[i] = *(const bf16x8*)&Ps[w][(i * 16 + l15) * 72 + kk + qd * 8];
#pragma unroll
            for (int jo = 0; jo < 8; jo++)
                vf[jo] = *(const bf16x8*)&Vts[(jo * 16 + l15) * 72 + kk + qd * 8];
#pragma unroll
            for (int i = 0; i < 2; i++) {
                lacc[i] = __builtin_amdgcn_mfma_f32_16x16x32_bf16(
                    pf[i], onef, lacc[i], 0, 0, 0);
#pragma unroll
                for (int jo = 0; jo < 8; jo++)
                    oacc[i][jo] = __builtin_amdgcn_mfma_f32_16x16x32_bf16(
                        pf[i], vf[jo], oacc[i][jo], 0, 0, 0);
            }
        }
    }

    // Epilogue: O / l, write to (B, T, H*D) for the output GEMM.
    // lacc[i][r] is column-uniform (every l15 lane holds its row's sum).
#pragma unroll
    for (int i = 0; i < 2; i++) {
#pragma unroll
        for (int r = 0; r < 4; r++) {
            float inv = 1.0f / lacc[i][r];
            int tg = qt * 128 + wrow + i * 16 + qd * 4 + r;
            size_t base = ((size_t)b * 2048 + tg) * 4096 + h * 128;
#pragma unroll
            for (int jo = 0; jo < 8; jo++)
                Oo[base + jo * 16 + l15] = f2bf(oacc[i][jo][r] * inv);
        }
    }
}

// ---------------------------------------------------------------------------
extern "C" void kernel_launch(void* const* d_in, const int* in_sizes, int n_in,
                              void* d_out, int out_size, void* d_ws, size_t ws_size,
                              hipStream_t stream) {
    const float* hidden = (const float*)d_in[0];  // (2,2048,4096) fp32
    const float* Wqkv   = (const float*)d_in[1];  // (5120, 4096)  fp32
    const float* Wo     = (const float*)d_in[2];  // (4096, 4096)  fp32
    const float* qw     = (const float*)d_in[3];  // (32, 128)     fp32
    const float* kw     = (const float*)d_in[4];  // (4, 128)      fp32
    float* out = (float*)d_out;                   // (2,2048,4096) fp32

    // Region plan (peak = 117,440,512 B):
    //   R0 [0, 41.9M):    Wqkv_bf (cvt->gemm1)  then  q_r/k_r/v_r (rms->flash)
    //   R1 [41.9M, 75.5M): hidden_bf (cvt->gemm1) then attn (flash->gemm2)
    //   R2 [75.5M, 117.4M): qkv (gemm1->rms)     then  Wo_bf (cvt->gemm2)
    char* ws = (char*)d_ws;
    bf16_t* Wqkv_bf   = (bf16_t*)ws;
    bf16_t* q_r       = (bf16_t*)ws;
    bf16_t* k_r       = (bf16_t*)(ws + 33554432ull);
    bf16_t* v_r       = (bf16_t*)(ws + 37748736ull);
    bf16_t* hidden_bf = (bf16_t*)(ws + 41943040ull);
    bf16_t* attn      = (bf16_t*)(ws + 41943040ull);
    bf16_t* qkv       = (bf16_t*)(ws + 75497472ull);
    bf16_t* Wo_bf     = (bf16_t*)(ws + 75497472ull);

    hipLaunchKernelGGL(cvt_f32_bf16, dim3(8192), dim3(256), 0, stream,
                       hidden, hidden_bf, 16777216 / 8);
    hipLaunchKernelGGL(cvt_f32_bf16, dim3(10240), dim3(256), 0, stream,
                       Wqkv, Wqkv_bf, 20971520 / 8);
    // 1) qkv = hidden @ Wqkv^T   M=4096 N=5120 K=4096
    hipLaunchKernelGGL((gemm_bt<bf16_t>), dim3(40, 32), dim3(256), 0, stream,
                       hidden_bf, Wqkv_bf, qkv, 4096, 5120, 4096);
    // 2) norm + RoPE + reshape (q pre-scaled by SCALE*log2e)
    hipLaunchKernelGGL(rmsrope, dim3(40960), dim3(256), 0, stream,
                       qkv, qw, kw, q_r, k_r, v_r);
    // 3) convert Wo into qkv's region (now dead)
    hipLaunchKernelGGL(cvt_f32_bf16, dim3(8192), dim3(256), 0, stream,
                       Wo, Wo_bf, 16777216 / 8);
    // 4) attention
    hipLaunchKernelGGL(flash_attn, dim3(16, 64), dim3(256), 0, stream,
                       q_r, k_r, v_r, attn);
    // 5) out = attn @ Wo^T   M=4096 N=4096 K=4096 (fp32 out)
    hipLaunchKernelGGL((gemm_bt<float>), dim3(32, 32), dim3(256), 0, stream,
                       attn, Wo_bf, out, 4096, 4096, 4096);
}

// Round 2
// 952.116 us; speedup vs baseline: 1.0590x; 1.0059x over previous
//
#include <hip/hip_runtime.h>

typedef __bf16 bf16_t;
typedef __bf16 bf16x4 __attribute__((ext_vector_type(4)));
typedef __bf16 bf16x8 __attribute__((ext_vector_type(8)));
typedef float floatx4 __attribute__((ext_vector_type(4)));

__device__ __forceinline__ float bf2f(bf16_t x) { return (float)x; }
__device__ __forceinline__ bf16_t f2bf(float x) { return (bf16_t)x; }

// async 16B global -> LDS (global_load_lds_dwordx4). LDS dst must be
// wave-uniform base + lane*16 (m97 pattern); global src may be per-lane.
__device__ __forceinline__ void async_copy16(const bf16_t* g, bf16_t* l) {
    __builtin_amdgcn_global_load_lds(
        (const __attribute__((address_space(1))) unsigned int*)g,
        (__attribute__((address_space(3))) unsigned int*)l, 16, 0, 0);
}

// 16-lane max-reduce on the VALU via DPP (no DS-pipe traffic, unlike
// __shfl_xor which lowers to ds_swizzle).  Steps: quad_perm xor1, xor2,
// row_half_mirror (combines quads in each 8), row_mirror (combines halves
// of the 16-lane row).  All lanes end with the 16-group max.
__device__ __forceinline__ float dpp_max16(float x) {
    float y;
    y = __builtin_bit_cast(float, __builtin_amdgcn_mov_dpp(
            __builtin_bit_cast(int, x), 0xB1, 0xF, 0xF, true));   // quad_perm 1,0,3,2
    x = fmaxf(x, y);
    y = __builtin_bit_cast(float, __builtin_amdgcn_mov_dpp(
            __builtin_bit_cast(int, x), 0x4E, 0xF, 0xF, true));   // quad_perm 2,3,0,1
    x = fmaxf(x, y);
    y = __builtin_bit_cast(float, __builtin_amdgcn_mov_dpp(
            __builtin_bit_cast(int, x), 0x141, 0xF, 0xF, true));  // row_half_mirror
    x = fmaxf(x, y);
    y = __builtin_bit_cast(float, __builtin_amdgcn_mov_dpp(
            __builtin_bit_cast(int, x), 0x140, 0xF, 0xF, true));  // row_mirror
    x = fmaxf(x, y);
    return x;
}

// ---------------------------------------------------------------------------
// fp32 -> bf16 elementwise convert (8 elems/thread, 16B stores). n8 = n/8.
// ---------------------------------------------------------------------------
__global__ __launch_bounds__(256) void cvt_f32_bf16(const float* __restrict__ in,
                                                    bf16_t* __restrict__ out,
                                                    int n8) {
    int i = blockIdx.x * blockDim.x + threadIdx.x;
    if (i >= n8) return;
    const float4* p = (const float4*)in + (size_t)i * 2;
    float4 a = p[0], b = p[1];
    bf16x8 v;
    v[0] = f2bf(a.x); v[1] = f2bf(a.y); v[2] = f2bf(a.z); v[3] = f2bf(a.w);
    v[4] = f2bf(b.x); v[5] = f2bf(b.y); v[6] = f2bf(b.z); v[7] = f2bf(b.w);
    *(bf16x8*)(out + (size_t)i * 8) = v;
}

// ---------------------------------------------------------------------------
// B^T GEMM, m97 structure: 128x128 tile, BK=32, 4 waves, 4x4 acc,
// global_load_lds width-16 staging.  (unchanged this round)
// ---------------------------------------------------------------------------
template <typename OT>
__global__ __launch_bounds__(256) void gemm_bt(const bf16_t* __restrict__ A,
                                               const bf16_t* __restrict__ B,
                                               OT* __restrict__ C,
                                               int M, int N, int K) {
    __shared__ __attribute__((aligned(16))) bf16_t As[128 * 32];
    __shared__ __attribute__((aligned(16))) bf16_t Bs[128 * 32];
    const int tid = threadIdx.x;
    const int lane = tid & 63;
    const int w = tid >> 6;
    const int l15 = lane & 15, qd = lane >> 4;
    const int tm = blockIdx.y * 128, tn = blockIdx.x * 128;
    const int wm = (w >> 1) * 64, wn = (w & 1) * 64;

    floatx4 acc[4][4] = {};

    for (int k0 = 0; k0 < K; k0 += 32) {
#pragma unroll
        for (int it = 0; it < 2; ++it) {
            int c = it * 256 + tid;          // 512 chunks of 16B per matrix
            int row = c >> 2, col = (c & 3) * 8;
            async_copy16(&A[(size_t)(tm + row) * K + k0 + col], &As[c * 8]);
            async_copy16(&B[(size_t)(tn + row) * K + k0 + col], &Bs[c * 8]);
        }
        __syncthreads();   // compiler emits vmcnt(0) drain before s_barrier
        bf16x8 af[4], bfr[4];
#pragma unroll
        for (int i = 0; i < 4; i++)
            af[i] = *(const bf16x8*)&As[(wm + i * 16 + l15) * 32 + qd * 8];
#pragma unroll
        for (int j = 0; j < 4; j++)
            bfr[j] = *(const bf16x8*)&Bs[(wn + j * 16 + l15) * 32 + qd * 8];
#pragma unroll
        for (int i = 0; i < 4; i++)
#pragma unroll
            for (int j = 0; j < 4; j++)
                acc[i][j] = __builtin_amdgcn_mfma_f32_16x16x32_bf16(
                    af[i], bfr[j], acc[i][j], 0, 0, 0);
        __syncthreads();
    }
    // C/D layout: col = lane&15, row = quad*4 + reg  (m89/m91 verified)
#pragma unroll
    for (int i = 0; i < 4; i++) {
        int row = tm + wm + i * 16 + qd * 4;
#pragma unroll
        for (int j = 0; j < 4; j++) {
            int col = tn + wn + j * 16 + l15;
#pragma unroll
            for (int r = 0; r < 4; r++)
                C[(size_t)(row + r) * N + col] = (OT)acc[i][j][r];
        }
    }
}

// ---------------------------------------------------------------------------
// Reference-faithful "norm" + RoPE + layout transform.
// The attention scale (1/sqrt(128)) AND log2(e) are folded into Q here
// (rope is linear, so scaling before the rotation is exact).  flash_attn then
// runs its softmax in base-2 with NO per-score scaling.
// ---------------------------------------------------------------------------
__global__ __launch_bounds__(256) void rmsrope(const bf16_t* __restrict__ qkv,
                                               const float* __restrict__ qw,
                                               const float* __restrict__ kw,
                                               bf16_t* __restrict__ q_r,
                                               bf16_t* __restrict__ k_r,
                                               bf16_t* __restrict__ v_r) {
    const int tid = threadIdx.x, lane = tid & 63, w = tid >> 6;
    const int slot = blockIdx.x * 4 + w;       // [0, 163840)
    const int row = slot / 40;
    const int hs = slot - row * 40;
    const int b = row >> 11, t = row & 2047;
    const bf16_t* src = qkv + (size_t)row * 5120 + hs * 128;

    if (hs >= 36) {  // v: passthrough reshape
        size_t dst = ((size_t)((b * 4 + (hs - 36)) * 2048 + t)) * 128;
        v_r[dst + lane] = src[lane];
        v_r[dst + lane + 64] = src[lane + 64];
        return;
    }
    float x1 = bf2f(src[lane]);
    float x2 = bf2f(src[lane + 64]);
    float ss = x1 * x1 + x2 * x2;
#pragma unroll
    for (int off = 1; off < 64; off <<= 1) ss += __shfl_xor(ss, off);
    const float rr = rsqrtf(ss * (1.0f / 128.0f) + 1e-6f);

    const float* wp;
    bf16_t* dstp;
    float sc;
    if (hs < 32) {
        wp = qw + hs * 128;
        dstp = q_r + ((size_t)((b * 32 + hs) * 2048 + t)) * 128;
        sc = rr * (0.08838834764831845f * 1.4426950408889634f);  // SCALE*log2e
    } else {
        wp = kw + (hs - 32) * 128;
        dstp = k_r + ((size_t)((b * 4 + (hs - 32)) * 2048 + t)) * 128;
        sc = rr;
    }
    float n1 = sc * wp[lane];
    float n2 = sc * wp[lane + 64];
    float inv_freq = exp2f((float)lane * -0.20762050593046f);
    float th = (float)t * inv_freq;
    float sn, cs;
    sincosf(th, &sn, &cs);
    dstp[lane] = f2bf(n1 * cs - n2 * sn);
    dstp[lane + 64] = f2bf(n1 * sn + n2 * cs);
}

// ---------------------------------------------------------------------------
// Flash attention v4.  This round (DS pipe + barrier drain were the limiter):
//  * Max-reduce butterfly moved off the DS pipe: dpp_max16 (VALU) replaces
//    __shfl_xor/ds_swizzle (-32 DS ops per wave-iter).
//  * T14 reg-prefetch for K AND V: the next tile's 8 global loads issue right
//    after barrier (B) and land during compute, so the staging section between
//    barriers has no load waits and (B)'s implicit vmcnt(0) is trivial.
//    K staging is now reg->LDS ds_write_b128 with the XOR swizzle applied on
//    the write address (rule #21: swizzle both sides; read side unchanged).
//  * Kept: ones-column row-sum MFMA, defer-max (T13), base-2 softmax with
//    pre-scaled Q, pi-shared P/V transpose trick.
// LDS: 16384 + 18432 + 18432 = 53248 B; 3 blocks/CU = 159744 <= 160K.
// ---------------------------------------------------------------------------
__global__ __launch_bounds__(256, 3) void flash_attn(const bf16_t* __restrict__ Qr,
                                                     const bf16_t* __restrict__ Kr,
                                                     const bf16_t* __restrict__ Vr,
                                                     bf16_t* __restrict__ Oo) {
    __shared__ __attribute__((aligned(16))) bf16_t Ks[64 * 128];   // XOR-swizzled
    __shared__ __attribute__((aligned(16))) bf16_t Vts[128 * 72];  // Vts[d][pi(k)]
    __shared__ __attribute__((aligned(16))) bf16_t Ps[4][32 * 72]; // Ps[q][pi(k)]
    const int tid = threadIdx.x, lane = tid & 63, w = tid >> 6;
    const int l15 = lane & 15, qd = lane >> 4;
    const int qt = blockIdx.x, bh = blockIdx.y;
    const int b = bh >> 5, h = bh & 31;
    const int kvh = h >> 3;  // GROUP = 8
    const bf16_t* Qb = Qr + ((size_t)(b * 32 + h) * 2048 + qt * 128) * 128;
    const bf16_t* Kb = Kr + ((size_t)(b * 4 + kvh) * 2048) * 128;
    const bf16_t* Vb = Vr + ((size_t)(b * 4 + kvh) * 2048) * 128;
    const int wrow = w * 32;
    const int pi = l15 * 4 + qd;            // pi(lane) for V transpose writes

    // Q fragments in registers: A[m=l15][k=qd*8+j], 32 rows x 128 k per wave.
    bf16x8 qf[2][4];
#pragma unroll
    for (int i = 0; i < 2; i++)
#pragma unroll
        for (int kk = 0; kk < 4; kk++)
            qf[i][kk] = *(const bf16x8*)&Qb[(size_t)(wrow + i * 16 + l15) * 128 +
                                            kk * 32 + qd * 8];

    bf16x8 onef;
#pragma unroll
    for (int e = 0; e < 8; ++e) onef[e] = f2bf(1.0f);

    // Prefetch tile 0's K and V into registers (T14).
    bf16x8 kreg[4], vreg[4];
#pragma unroll
    for (int it = 0; it < 4; ++it) {
        int cc = it * 256 + tid;
        int row = cc >> 4;
        kreg[it] = *(const bf16x8*)&Kb[(size_t)row * 128 + (cc & 15) * 8];
        vreg[it] = *(const bf16x8*)&Vb[(size_t)lane * 128 + (it * 4 + w) * 8];
    }

    float m_s[2][4];
    floatx4 lacc[2] = {};        // row-sums, accumulated by ones-column MFMA
    floatx4 oacc[2][8] = {};
#pragma unroll
    for (int i = 0; i < 2; i++)
#pragma unroll
        for (int r = 0; r < 4; r++) m_s[i][r] = -1e30f;

    for (int kt = 0; kt < 32; ++kt) {
        __syncthreads();  // (A) prev iteration's reads of Ks/Vts done
        // K tile from regs -> Ks with write-side XOR swizzle (read matches).
#pragma unroll
        for (int it = 0; it < 4; ++it) {
            int cc = it * 256 + tid;
            int row = cc >> 4;
            int xb = ((cc & 15) * 16) ^ ((row & 7) << 4);
            *(bf16x8*)&Ks[row * 128 + (xb >> 1)] = kreg[it];
        }
        // V tile from regs -> Vts transposed with pi: Vts[d][pi(k)] = V[k][d]
#pragma unroll
        for (int it = 0; it < 4; ++it) {
            int d0 = (it * 4 + w) * 8;
#pragma unroll
            for (int e = 0; e < 8; ++e) Vts[(d0 + e) * 72 + pi] = vreg[it][e];
        }
        __syncthreads();  // (B) lgkm drain only; no outstanding vmem here

        // Prefetch next tile's K/V into regs; lands during compute below.
        {
            int ktn = (kt + 1 < 32) ? kt + 1 : kt;
#pragma unroll
            for (int it = 0; it < 4; ++it) {
                int cc = it * 256 + tid;
                int row = cc >> 4;
                kreg[it] = *(const bf16x8*)&Kb[(size_t)(ktn * 64 + row) * 128 +
                                               (cc & 15) * 8];
                vreg[it] = *(const bf16x8*)&Vb[(size_t)(ktn * 64 + lane) * 128 +
                                               (it * 4 + w) * 8];
            }
        }

        // S = Q K^T for this wave's 32 rows x 64 keys (scores pre-scaled)
        floatx4 sacc[2][4] = {};
#pragma unroll
        for (int kk = 0; kk < 4; kk++) {
            bf16x8 bfr[4];
#pragma unroll
            for (int j = 0; j < 4; j++) {
                int rr2 = j * 16 + l15;
                int xb = (kk * 64 + qd * 16) ^ ((rr2 & 7) << 4);
                bfr[j] = *(const bf16x8*)&Ks[rr2 * 128 + (xb >> 1)];
            }
#pragma unroll
            for (int i = 0; i < 2; i++)
#pragma unroll
                for (int j = 0; j < 4; j++)
                    sacc[i][j] = __builtin_amdgcn_mfma_f32_16x16x32_bf16(
                        qf[i][kk], bfr[j], sacc[i][j], 0, 0, 0);
        }

        // Pass 1: per-row tile max via DPP (VALU pipe, no DS traffic).
        float mxv[2][4];
        int fneed = 0;
#pragma unroll
        for (int i = 0; i < 2; i++)
#pragma unroll
            for (int r = 0; r < 4; r++) {
                float mx = fmaxf(fmaxf(sacc[i][0][r], sacc[i][1][r]),
                                 fmaxf(sacc[i][2][r], sacc[i][3][r]));
                mx = dpp_max16(mx);
                mxv[i][r] = mx;
                fneed |= (mx > m_s[i][r] + 11.5f);   // 8 nats in log2 units
            }
        // Defer-max: wave-uniform rescale only when some row's max grew.
        if (__any(fneed)) {
#pragma unroll
            for (int i = 0; i < 2; i++)
#pragma unroll
                for (int r = 0; r < 4; r++) {
                    float mnew = fmaxf(m_s[i][r], mxv[i][r]);
                    float alpha = exp2f(m_s[i][r] - mnew);
                    m_s[i][r] = mnew;
#pragma unroll
                    for (int jo = 0; jo < 8; jo++) oacc[i][jo][r] *= alpha;
                    lacc[i][r] *= alpha;
                }
        }
        // Pass 2: P = 2^(s - m), bf16, one 8B store per row (pi-order).
#pragma unroll
        for (int i = 0; i < 2; i++)
#pragma unroll
            for (int r = 0; r < 4; r++) {
                float m = m_s[i][r];
                bf16x4 pv;
                pv[0] = f2bf(exp2f(sacc[i][0][r] - m));
                pv[1] = f2bf(exp2f(sacc[i][1][r] - m));
                pv[2] = f2bf(exp2f(sacc[i][2][r] - m));
                pv[3] = f2bf(exp2f(sacc[i][3][r] - m));
                *(bf16x4*)&Ps[w][(i * 16 + qd * 4 + r) * 72 + l15 * 4] = pv;
            }
        // No barrier: Ps[w] is wave-private; same-wave DS ops are ordered.

        // O += P V ; l += P 1  (ones-column replaces the sum shuffle-reduce)
#pragma unroll
        for (int kk = 0; kk < 64; kk += 32) {
            bf16x8 pf[2], vf[8];
#pragma unroll
            for (int i = 0; i < 2; i++)
                pf[i] = *(const bf16x8*)&Ps[w][(i * 16 + l15) * 72 + kk + qd * 8];
#pragma unroll
            for (int jo = 0; jo < 8; jo++)
                vf[jo] = *(const bf16x8*)&Vts[(jo * 16 + l15) * 72 + kk + qd * 8];
#pragma unroll
            for (int i = 0; i < 2; i++) {
                lacc[i] = __builtin_amdgcn_mfma_f32_16x16x32_bf16(
                    pf[i], onef, lacc[i], 0, 0, 0);
#pragma unroll
                for (int jo = 0; jo < 8; jo++)
                    oacc[i][jo] = __builtin_amdgcn_mfma_f32_16x16x32_bf16(
                        pf[i], vf[jo], oacc[i][jo], 0, 0, 0);
            }
        }
    }

    // Epilogue: O / l, write to (B, T, H*D) for the output GEMM.
    // lacc[i][r] is column-uniform (every l15 lane holds its row's sum).
#pragma unroll
    for (int i = 0; i < 2; i++) {
#pragma unroll
        for (int r = 0; r < 4; r++) {
            float inv = 1.0f / lacc[i][r];
            int tg = qt * 128 + wrow + i * 16 + qd * 4 + r;
            size_t base = ((size_t)b * 2048 + tg) * 4096 + h * 128;
#pragma unroll
            for (int jo = 0; jo < 8; jo++)
                Oo[base + jo * 16 + l15] = f2bf(oacc[i][jo][r] * inv);
        }
    }
}

// ---------------------------------------------------------------------------
extern "C" void kernel_launch(void* const* d_in, const int* in_sizes, int n_in,
                              void* d_out, int out_size, void* d_ws, size_t ws_size,
                              hipStream_t stream) {
    const float* hidden = (const float*)d_in[0];  // (2,2048,4096) fp32
    const float* Wqkv   = (const float*)d_in[1];  // (5120, 4096)  fp32
    const float* Wo     = (const float*)d_in[2];  // (4096, 4096)  fp32
    const float* qw     = (const float*)d_in[3];  // (32, 128)     fp32
    const float* kw     = (const float*)d_in[4];  // (4, 128)      fp32
    float* out = (float*)d_out;                   // (2,2048,4096) fp32

    // Region plan (peak = 117,440,512 B):
    //   R0 [0, 41.9M):    Wqkv_bf (cvt->gemm1)  then  q_r/k_r/v_r (rms->flash)
    //   R1 [41.9M, 75.5M): hidden_bf (cvt->gemm1) then attn (flash->gemm2)
    //   R2 [75.5M, 117.4M): qkv (gemm1->rms)     then  Wo_bf (cvt->gemm2)
    char* ws = (char*)d_ws;
    bf16_t* Wqkv_bf   = (bf16_t*)ws;
    bf16_t* q_r       = (bf16_t*)ws;
    bf16_t* k_r       = (bf16_t*)(ws + 33554432ull);
    bf16_t* v_r       = (bf16_t*)(ws + 37748736ull);
    bf16_t* hidden_bf = (bf16_t*)(ws + 41943040ull);
    bf16_t* attn      = (bf16_t*)(ws + 41943040ull);
    bf16_t* qkv       = (bf16_t*)(ws + 75497472ull);
    bf16_t* Wo_bf     = (bf16_t*)(ws + 75497472ull);

    hipLaunchKernelGGL(cvt_f32_bf16, dim3(8192), dim3(256), 0, stream,
                       hidden, hidden_bf, 16777216 / 8);
    hipLaunchKernelGGL(cvt_f32_bf16, dim3(10240), dim3(256), 0, stream,
                       Wqkv, Wqkv_bf, 20971520 / 8);
    // 1) qkv = hidden @ Wqkv^T   M=4096 N=5120 K=4096
    hipLaunchKernelGGL((gemm_bt<bf16_t>), dim3(40, 32), dim3(256), 0, stream,
                       hidden_bf, Wqkv_bf, qkv, 4096, 5120, 4096);
    // 2) norm + RoPE + reshape (q pre-scaled by SCALE*log2e)
    hipLaunchKernelGGL(rmsrope, dim3(40960), dim3(256), 0, stream,
                       qkv, qw, kw, q_r, k_r, v_r);
    // 3) convert Wo into qkv's region (now dead)
    hipLaunchKernelGGL(cvt_f32_bf16, dim3(8192), dim3(256), 0, stream,
                       Wo, Wo_bf, 16777216 / 8);
    // 4) attention
    hipLaunchKernelGGL(flash_attn, dim3(16, 64), dim3(256), 0, stream,
                       q_r, k_r, v_r, attn);
    // 5) out = attn @ Wo^T   M=4096 N=4096 K=4096 (fp32 out)
    hipLaunchKernelGGL((gemm_bt<float>), dim3(32, 32), dim3(256), 0, stream,
                       attn, Wo_bf, out, 4096, 4096, 4096);
}

// Round 3
// 912.957 us; speedup vs baseline: 1.1044x; 1.0429x over previous
//
#include <hip/hip_runtime.h>

typedef __bf16 bf16_t;
typedef __bf16 bf16x4 __attribute__((ext_vector_type(4)));
typedef __bf16 bf16x8 __attribute__((ext_vector_type(8)));
typedef float floatx4 __attribute__((ext_vector_type(4)));

__device__ __forceinline__ float bf2f(bf16_t x) { return (float)x; }
__device__ __forceinline__ bf16_t f2bf(float x) { return (bf16_t)x; }

// async 16B global -> LDS (global_load_lds_dwordx4). LDS dst must be
// wave-uniform base + lane*16 (m97 pattern); global src may be per-lane.
__device__ __forceinline__ void async_copy16(const bf16_t* g, bf16_t* l) {
    __builtin_amdgcn_global_load_lds(
        (const __attribute__((address_space(1))) unsigned int*)g,
        (__attribute__((address_space(3))) unsigned int*)l, 16, 0, 0);
}

// 16-lane max-reduce on the VALU via DPP (no DS-pipe traffic, unlike
// __shfl_xor which lowers to ds_swizzle).
__device__ __forceinline__ float dpp_max16(float x) {
    float y;
    y = __builtin_bit_cast(float, __builtin_amdgcn_mov_dpp(
            __builtin_bit_cast(int, x), 0xB1, 0xF, 0xF, true));   // quad_perm 1,0,3,2
    x = fmaxf(x, y);
    y = __builtin_bit_cast(float, __builtin_amdgcn_mov_dpp(
            __builtin_bit_cast(int, x), 0x4E, 0xF, 0xF, true));   // quad_perm 2,3,0,1
    x = fmaxf(x, y);
    y = __builtin_bit_cast(float, __builtin_amdgcn_mov_dpp(
            __builtin_bit_cast(int, x), 0x141, 0xF, 0xF, true));  // row_half_mirror
    x = fmaxf(x, y);
    y = __builtin_bit_cast(float, __builtin_amdgcn_mov_dpp(
            __builtin_bit_cast(int, x), 0x140, 0xF, 0xF, true));  // row_mirror
    x = fmaxf(x, y);
    return x;
}

// ---------------------------------------------------------------------------
// fp32 -> bf16 elementwise convert (8 elems/thread, 16B stores). n8 = n/8.
// ---------------------------------------------------------------------------
__global__ __launch_bounds__(256) void cvt_f32_bf16(const float* __restrict__ in,
                                                    bf16_t* __restrict__ out,
                                                    int n8) {
    int i = blockIdx.x * blockDim.x + threadIdx.x;
    if (i >= n8) return;
    const float4* p = (const float4*)in + (size_t)i * 2;
    float4 a = p[0], b = p[1];
    bf16x8 v;
    v[0] = f2bf(a.x); v[1] = f2bf(a.y); v[2] = f2bf(a.z); v[3] = f2bf(a.w);
    v[4] = f2bf(b.x); v[5] = f2bf(b.y); v[6] = f2bf(b.z); v[7] = f2bf(b.w);
    *(bf16x8*)(out + (size_t)i * 8) = v;
}

// ---------------------------------------------------------------------------
// B^T GEMM, m97 structure: 128x128 tile, BK=32, 4 waves, 4x4 acc,
// global_load_lds width-16 staging.  (unchanged this round)
// ---------------------------------------------------------------------------
template <typename OT>
__global__ __launch_bounds__(256) void gemm_bt(const bf16_t* __restrict__ A,
                                               const bf16_t* __restrict__ B,
                                               OT* __restrict__ C,
                                               int M, int N, int K) {
    __shared__ __attribute__((aligned(16))) bf16_t As[128 * 32];
    __shared__ __attribute__((aligned(16))) bf16_t Bs[128 * 32];
    const int tid = threadIdx.x;
    const int lane = tid & 63;
    const int w = tid >> 6;
    const int l15 = lane & 15, qd = lane >> 4;
    const int tm = blockIdx.y * 128, tn = blockIdx.x * 128;
    const int wm = (w >> 1) * 64, wn = (w & 1) * 64;

    floatx4 acc[4][4] = {};

    for (int k0 = 0; k0 < K; k0 += 32) {
#pragma unroll
        for (int it = 0; it < 2; ++it) {
            int c = it * 256 + tid;          // 512 chunks of 16B per matrix
            int row = c >> 2, col = (c & 3) * 8;
            async_copy16(&A[(size_t)(tm + row) * K + k0 + col], &As[c * 8]);
            async_copy16(&B[(size_t)(tn + row) * K + k0 + col], &Bs[c * 8]);
        }
        __syncthreads();   // compiler emits vmcnt(0) drain before s_barrier
        bf16x8 af[4], bfr[4];
#pragma unroll
        for (int i = 0; i < 4; i++)
            af[i] = *(const bf16x8*)&As[(wm + i * 16 + l15) * 32 + qd * 8];
#pragma unroll
        for (int j = 0; j < 4; j++)
            bfr[j] = *(const bf16x8*)&Bs[(wn + j * 16 + l15) * 32 + qd * 8];
#pragma unroll
        for (int i = 0; i < 4; i++)
#pragma unroll
            for (int j = 0; j < 4; j++)
                acc[i][j] = __builtin_amdgcn_mfma_f32_16x16x32_bf16(
                    af[i], bfr[j], acc[i][j], 0, 0, 0);
        __syncthreads();
    }
    // C/D layout: col = lane&15, row = quad*4 + reg  (m89/m91 verified)
#pragma unroll
    for (int i = 0; i < 4; i++) {
        int row = tm + wm + i * 16 + qd * 4;
#pragma unroll
        for (int j = 0; j < 4; j++) {
            int col = tn + wn + j * 16 + l15;
#pragma unroll
            for (int r = 0; r < 4; r++)
                C[(size_t)(row + r) * N + col] = (OT)acc[i][j][r];
        }
    }
}

// ---------------------------------------------------------------------------
// Reference-faithful "norm" + RoPE + layout transform.
// The attention scale (1/sqrt(128)) AND log2(e) are folded into Q here
// (rope is linear, so scaling before the rotation is exact).  flash_attn then
// runs its softmax in base-2 with NO per-score scaling.
// ---------------------------------------------------------------------------
__global__ __launch_bounds__(256) void rmsrope(const bf16_t* __restrict__ qkv,
                                               const float* __restrict__ qw,
                                               const float* __restrict__ kw,
                                               bf16_t* __restrict__ q_r,
                                               bf16_t* __restrict__ k_r,
                                               bf16_t* __restrict__ v_r) {
    const int tid = threadIdx.x, lane = tid & 63, w = tid >> 6;
    const int slot = blockIdx.x * 4 + w;       // [0, 163840)
    const int row = slot / 40;
    const int hs = slot - row * 40;
    const int b = row >> 11, t = row & 2047;
    const bf16_t* src = qkv + (size_t)row * 5120 + hs * 128;

    if (hs >= 36) {  // v: passthrough reshape
        size_t dst = ((size_t)((b * 4 + (hs - 36)) * 2048 + t)) * 128;
        v_r[dst + lane] = src[lane];
        v_r[dst + lane + 64] = src[lane + 64];
        return;
    }
    float x1 = bf2f(src[lane]);
    float x2 = bf2f(src[lane + 64]);
    float ss = x1 * x1 + x2 * x2;
#pragma unroll
    for (int off = 1; off < 64; off <<= 1) ss += __shfl_xor(ss, off);
    const float rr = rsqrtf(ss * (1.0f / 128.0f) + 1e-6f);

    const float* wp;
    bf16_t* dstp;
    float sc;
    if (hs < 32) {
        wp = qw + hs * 128;
        dstp = q_r + ((size_t)((b * 32 + hs) * 2048 + t)) * 128;
        sc = rr * (0.08838834764831845f * 1.4426950408889634f);  // SCALE*log2e
    } else {
        wp = kw + (hs - 32) * 128;
        dstp = k_r + ((size_t)((b * 4 + (hs - 32)) * 2048 + t)) * 128;
        sc = rr;
    }
    float n1 = sc * wp[lane];
    float n2 = sc * wp[lane + 64];
    float inv_freq = exp2f((float)lane * -0.20762050593046f);
    float th = (float)t * inv_freq;
    float sn, cs;
    sincosf(th, &sn, &cs);
    dstp[lane] = f2bf(n1 * cs - n2 * sn);
    dstp[lane + 64] = f2bf(n1 * sn + n2 * cs);
}

// ---------------------------------------------------------------------------
// Flash attention v5.  Round-2 regression was VGPR squeeze (launch_bounds
// (256,3) -> 84 VGPR -> scratch spills: WRITE_SIZE +29MB).  This round:
//  * Back to __launch_bounds__(256, 2): no spill (need ~140 VGPR).
//  * K via global_load_lds DMA again (zero VGPR, zero ds_writes) but into a
//    DOUBLE-buffered Ks: tile kt+1's DMA issues right after barrier (B), so
//    the whole compute section covers its latency, and the vmcnt(0) the
//    compiler emits before each s_barrier finds it already landed.  With a
//    single buffer the DMA could only issue between the barriers -> its
//    latency was exposed every iteration (rounds 0-1).
//  * V reg-prefetch kept (issued after (B), consumed at next iter's scatter).
//  * Kept: DPP max-reduce, ones-column row-sum MFMA, defer-max, base-2
//    softmax with pre-scaled Q, pi-shared P/V transpose trick.
// LDS: 2*16384 + 18432 + 18432 = 69632 B; 2 blocks/CU = 139264 <= 160K.
// ---------------------------------------------------------------------------
__global__ __launch_bounds__(256, 2) void flash_attn(const bf16_t* __restrict__ Qr,
                                                     const bf16_t* __restrict__ Kr,
                                                     const bf16_t* __restrict__ Vr,
                                                     bf16_t* __restrict__ Oo) {
    __shared__ __attribute__((aligned(16))) bf16_t Ks[2][64 * 128]; // XOR-swizzled
    __shared__ __attribute__((aligned(16))) bf16_t Vts[128 * 72];   // Vts[d][pi(k)]
    __shared__ __attribute__((aligned(16))) bf16_t Ps[4][32 * 72];  // Ps[q][pi(k)]
    const int tid = threadIdx.x, lane = tid & 63, w = tid >> 6;
    const int l15 = lane & 15, qd = lane >> 4;
    const int qt = blockIdx.x, bh = blockIdx.y;
    const int b = bh >> 5, h = bh & 31;
    const int kvh = h >> 3;  // GROUP = 8
    const bf16_t* Qb = Qr + ((size_t)(b * 32 + h) * 2048 + qt * 128) * 128;
    const bf16_t* Kb = Kr + ((size_t)(b * 4 + kvh) * 2048) * 128;
    const bf16_t* Vb = Vr + ((size_t)(b * 4 + kvh) * 2048) * 128;
    const int wrow = w * 32;
    const int pi = l15 * 4 + qd;            // pi(lane) for V transpose writes

    // Q fragments in registers: A[m=l15][k=qd*8+j], 32 rows x 128 k per wave.
    bf16x8 qf[2][4];
#pragma unroll
    for (int i = 0; i < 2; i++)
#pragma unroll
        for (int kk = 0; kk < 4; kk++)
            qf[i][kk] = *(const bf16x8*)&Qb[(size_t)(wrow + i * 16 + l15) * 128 +
                                            kk * 32 + qd * 8];

    bf16x8 onef;
#pragma unroll
    for (int e = 0; e < 8; ++e) onef[e] = f2bf(1.0f);

    // Prefetch tile 0: K via DMA into Ks[0] (pre-swizzled source), V to regs.
#pragma unroll
    for (int it = 0; it < 4; ++it) {
        int cc = it * 256 + tid;                 // 1024 chunks of 16B
        int row = cc >> 4;
        int xb = ((cc & 15) * 16) ^ ((row & 7) << 4);
        async_copy16(&Kb[(size_t)row * 128 + (xb >> 1)], &Ks[0][cc * 8]);
    }
    bf16x8 vreg[4];
#pragma unroll
    for (int it = 0; it < 4; ++it)
        vreg[it] = *(const bf16x8*)&Vb[(size_t)lane * 128 + (it * 4 + w) * 8];

    float m_s[2][4];
    floatx4 lacc[2] = {};        // row-sums, accumulated by ones-column MFMA
    floatx4 oacc[2][8] = {};
#pragma unroll
    for (int i = 0; i < 2; i++)
#pragma unroll
        for (int r = 0; r < 4; r++) m_s[i][r] = -1e30f;

    for (int kt = 0; kt < 32; ++kt) {
        const bf16_t* Kcur = Ks[kt & 1];
        __syncthreads();  // (A) prev compute done; drains K-DMA[kt]+vreg[kt]
        // V tile from regs -> Vts transposed with pi: Vts[d][pi(k)] = V[k][d]
#pragma unroll
        for (int it = 0; it < 4; ++it) {
            int d0 = (it * 4 + w) * 8;
#pragma unroll
            for (int e = 0; e < 8; ++e) Vts[(d0 + e) * 72 + pi] = vreg[it][e];
        }
        __syncthreads();  // (B) lgkm drain only; no outstanding vmem here

        // Prefetch tile kt+1 (lands during compute below, drained at next (A)).
        // Ks[1-cur] was last read before (A) of this iter -> safe to fill now.
        if (kt + 1 < 32) {
            bf16_t* Kn = Ks[(kt + 1) & 1];
#pragma unroll
            for (int it = 0; it < 4; ++it) {
                int cc = it * 256 + tid;
                int row = cc >> 4;
                int xb = ((cc & 15) * 16) ^ ((row & 7) << 4);
                async_copy16(&Kb[(size_t)((kt + 1) * 64 + row) * 128 + (xb >> 1)],
                             &Kn[cc * 8]);
            }
#pragma unroll
            for (int it = 0; it < 4; ++it)
                vreg[it] = *(const bf16x8*)&Vb[(size_t)((kt + 1) * 64 + lane) * 128 +
                                               (it * 4 + w) * 8];
        }

        // S = Q K^T for this wave's 32 rows x 64 keys (scores pre-scaled)
        floatx4 sacc[2][4] = {};
#pragma unroll
        for (int kk = 0; kk < 4; kk++) {
            bf16x8 bfr[4];
#pragma unroll
            for (int j = 0; j < 4; j++) {
                int rr2 = j * 16 + l15;
                int xb = (kk * 64 + qd * 16) ^ ((rr2 & 7) << 4);
                bfr[j] = *(const bf16x8*)&Kcur[rr2 * 128 + (xb >> 1)];
            }
#pragma unroll
            for (int i = 0; i < 2; i++)
#pragma unroll
                for (int j = 0; j < 4; j++)
                    sacc[i][j] = __builtin_amdgcn_mfma_f32_16x16x32_bf16(
                        qf[i][kk], bfr[j], sacc[i][j], 0, 0, 0);
        }

        // Pass 1: per-row tile max via DPP (VALU pipe, no DS traffic).
        float mxv[2][4];
        int fneed = 0;
#pragma unroll
        for (int i = 0; i < 2; i++)
#pragma unroll
            for (int r = 0; r < 4; r++) {
                float mx = fmaxf(fmaxf(sacc[i][0][r], sacc[i][1][r]),
                                 fmaxf(sacc[i][2][r], sacc[i][3][r]));
                mx = dpp_max16(mx);
                mxv[i][r] = mx;
                fneed |= (mx > m_s[i][r] + 11.5f);   // 8 nats in log2 units
            }
        // Defer-max: wave-uniform rescale only when some row's max grew.
        if (__any(fneed)) {
#pragma unroll
            for (int i = 0; i < 2; i++)
#pragma unroll
                for (int r = 0; r < 4; r++) {
                    float mnew = fmaxf(m_s[i][r], mxv[i][r]);
                    float alpha = exp2f(m_s[i][r] - mnew);
                    m_s[i][r] = mnew;
#pragma unroll
                    for (int jo = 0; jo < 8; jo++) oacc[i][jo][r] *= alpha;
                    lacc[i][r] *= alpha;
                }
        }
        // Pass 2: P = 2^(s - m), bf16, one 8B store per row (pi-order).
#pragma unroll
        for (int i = 0; i < 2; i++)
#pragma unroll
            for (int r = 0; r < 4; r++) {
                float m = m_s[i][r];
                bf16x4 pv;
                pv[0] = f2bf(exp2f(sacc[i][0][r] - m));
                pv[1] = f2bf(exp2f(sacc[i][1][r] - m));
                pv[2] = f2bf(exp2f(sacc[i][2][r] - m));
                pv[3] = f2bf(exp2f(sacc[i][3][r] - m));
                *(bf16x4*)&Ps[w][(i * 16 + qd * 4 + r) * 72 + l15 * 4] = pv;
            }
        // No barrier: Ps[w] is wave-private; same-wave DS ops are ordered.

        // O += P V ; l += P 1  (ones-column replaces the sum shuffle-reduce)
#pragma unroll
        for (int kk = 0; kk < 64; kk += 32) {
            bf16x8 pf[2], vf[8];
#pragma unroll
            for (int i = 0; i < 2; i++)
                pf[i] = *(const bf16x8*)&Ps[w][(i * 16 + l15) * 72 + kk + qd * 8];
#pragma unroll
            for (int jo = 0; jo < 8; jo++)
                vf[jo] = *(const bf16x8*)&Vts[(jo * 16 + l15) * 72 + kk + qd * 8];
#pragma unroll
            for (int i = 0; i < 2; i++) {
                lacc[i] = __builtin_amdgcn_mfma_f32_16x16x32_bf16(
                    pf[i], onef, lacc[i], 0, 0, 0);
#pragma unroll
                for (int jo = 0; jo < 8; jo++)
                    oacc[i][jo] = __builtin_amdgcn_mfma_f32_16x16x32_bf16(
                        pf[i], vf[jo], oacc[i][jo], 0, 0, 0);
            }
        }
    }

    // Epilogue: O / l, write to (B, T, H*D) for the output GEMM.
    // lacc[i][r] is column-uniform (every l15 lane holds its row's sum).
#pragma unroll
    for (int i = 0; i < 2; i++) {
#pragma unroll
        for (int r = 0; r < 4; r++) {
            float inv = 1.0f / lacc[i][r];
            int tg = qt * 128 + wrow + i * 16 + qd * 4 + r;
            size_t base = ((size_t)b * 2048 + tg) * 4096 + h * 128;
#pragma unroll
            for (int jo = 0; jo < 8; jo++)
                Oo[base + jo * 16 + l15] = f2bf(oacc[i][jo][r] * inv);
        }
    }
}

// ---------------------------------------------------------------------------
extern "C" void kernel_launch(void* const* d_in, const int* in_sizes, int n_in,
                              void* d_out, int out_size, void* d_ws, size_t ws_size,
                              hipStream_t stream) {
    const float* hidden = (const float*)d_in[0];  // (2,2048,4096) fp32
    const float* Wqkv   = (const float*)d_in[1];  // (5120, 4096)  fp32
    const float* Wo     = (const float*)d_in[2];  // (4096, 4096)  fp32
    const float* qw     = (const float*)d_in[3];  // (32, 128)     fp32
    const float* kw     = (const float*)d_in[4];  // (4, 128)      fp32
    float* out = (float*)d_out;                   // (2,2048,4096) fp32

    // Region plan (peak = 117,440,512 B):
    //   R0 [0, 41.9M):    Wqkv_bf (cvt->gemm1)  then  q_r/k_r/v_r (rms->flash)
    //   R1 [41.9M, 75.5M): hidden_bf (cvt->gemm1) then attn (flash->gemm2)
    //   R2 [75.5M, 117.4M): qkv (gemm1->rms)     then  Wo_bf (cvt->gemm2)
    char* ws = (char*)d_ws;
    bf16_t* Wqkv_bf   = (bf16_t*)ws;
    bf16_t* q_r       = (bf16_t*)ws;
    bf16_t* k_r       = (bf16_t*)(ws + 33554432ull);
    bf16_t* v_r       = (bf16_t*)(ws + 37748736ull);
    bf16_t* hidden_bf = (bf16_t*)(ws + 41943040ull);
    bf16_t* attn      = (bf16_t*)(ws + 41943040ull);
    bf16_t* qkv       = (bf16_t*)(ws + 75497472ull);
    bf16_t* Wo_bf     = (bf16_t*)(ws + 75497472ull);

    hipLaunchKernelGGL(cvt_f32_bf16, dim3(8192), dim3(256), 0, stream,
                       hidden, hidden_bf, 16777216 / 8);
    hipLaunchKernelGGL(cvt_f32_bf16, dim3(10240), dim3(256), 0, stream,
                       Wqkv, Wqkv_bf, 20971520 / 8);
    // 1) qkv = hidden @ Wqkv^T   M=4096 N=5120 K=4096
    hipLaunchKernelGGL((gemm_bt<bf16_t>), dim3(40, 32), dim3(256), 0, stream,
                       hidden_bf, Wqkv_bf, qkv, 4096, 5120, 4096);
    // 2) norm + RoPE + reshape (q pre-scaled by SCALE*log2e)
    hipLaunchKernelGGL(rmsrope, dim3(40960), dim3(256), 0, stream,
                       qkv, qw, kw, q_r, k_r, v_r);
    // 3) convert Wo into qkv's region (now dead)
    hipLaunchKernelGGL(cvt_f32_bf16, dim3(8192), dim3(256), 0, stream,
                       Wo, Wo_bf, 16777216 / 8);
    // 4) attention
    hipLaunchKernelGGL(flash_attn, dim3(16, 64), dim3(256), 0, stream,
                       q_r, k_r, v_r, attn);
    // 5) out = attn @ Wo^T   M=4096 N=4096 K=4096 (fp32 out)
    hipLaunchKernelGGL((gemm_bt<float>), dim3(32, 32), dim3(256), 0, stream,
                       attn, Wo_bf, out, 4096, 4096, 4096);
}